// Round 1
// baseline (5566.035 us; speedup 1.0000x reference)
//
#include <hip/hip_runtime.h>

#define BB 32
#define NN 576
#define DD 1024
#define KK 128
#define HS_N 577

// ---------------- norm kernel: inv[b,n] = 1/||feats[b,n,:]|| ----------------
__global__ __launch_bounds__(256) void norm_kernel(const float* __restrict__ hs,
                                                   float* __restrict__ inv) {
    int row = blockIdx.x;              // b*NN + n
    int b = row / NN, n = row % NN;
    const float4* p = (const float4*)(hs + ((size_t)b * HS_N + n + 1) * DD);
    int t = threadIdx.x;
    float4 v = p[t];
    double s = (double)v.x * v.x + (double)v.y * v.y + (double)v.z * v.z + (double)v.w * v.w;
    for (int off = 32; off; off >>= 1) s += __shfl_xor(s, off);
    __shared__ double wsum[4];
    int lane = t & 63, w = t >> 6;
    if (lane == 0) wsum[w] = s;
    __syncthreads();
    if (t == 0) {
        double tot = wsum[0] + wsum[1] + wsum[2] + wsum[3];
        inv[row] = 1.0f / (float)sqrt(tot);
    }
}

// ---------------- sim GEMM: sim[b,m,n] = dot(norm_m, norm_n) ----------------
#define KC 16
#define LDT 68   // padded LDS stride: float4-aligned, write conflicts only 2-way (free)
__global__ __launch_bounds__(256) void sim_kernel(const float* __restrict__ hs,
                                                  const float* __restrict__ inv,
                                                  float* __restrict__ sim) {
    int b = blockIdx.z;
    int m0 = blockIdx.x * 64, n0 = blockIdx.y * 64;
    const float* feats = hs + ((size_t)b * HS_N + 1) * DD;
    __shared__ float As[KC * LDT];
    __shared__ float Bs[KC * LDT];
    int t = threadIdx.x;
    int lrow = t >> 2, lc4 = (t & 3) << 2;     // 64 rows x 4 float4-cols
    float invA = inv[b * NN + m0 + lrow];
    float invB = inv[b * NN + n0 + lrow];
    const float* gA = feats + (size_t)(m0 + lrow) * DD + lc4;
    const float* gB = feats + (size_t)(n0 + lrow) * DD + lc4;
    int tx = t & 15, ty = t >> 4;
    float acc[4][4] = {};
    for (int k0 = 0; k0 < DD; k0 += KC) {
        float4 a = *(const float4*)(gA + k0);
        float4 bv = *(const float4*)(gB + k0);
        __syncthreads();
        // store transposed [k][m], scaled at load (matches reference's normalize-then-dot)
        As[(lc4 + 0) * LDT + lrow] = a.x * invA;
        As[(lc4 + 1) * LDT + lrow] = a.y * invA;
        As[(lc4 + 2) * LDT + lrow] = a.z * invA;
        As[(lc4 + 3) * LDT + lrow] = a.w * invA;
        Bs[(lc4 + 0) * LDT + lrow] = bv.x * invB;
        Bs[(lc4 + 1) * LDT + lrow] = bv.y * invB;
        Bs[(lc4 + 2) * LDT + lrow] = bv.z * invB;
        Bs[(lc4 + 3) * LDT + lrow] = bv.w * invB;
        __syncthreads();
#pragma unroll
        for (int kk = 0; kk < KC; kk++) {
            float4 av = *(const float4*)&As[kk * LDT + (tx << 2)];
            float4 bw = *(const float4*)&Bs[kk * LDT + (ty << 2)];
            float aa[4] = {av.x, av.y, av.z, av.w};
            float bb[4] = {bw.x, bw.y, bw.z, bw.w};
#pragma unroll
            for (int i = 0; i < 4; i++)
#pragma unroll
                for (int j = 0; j < 4; j++) acc[i][j] += aa[i] * bb[j];
        }
    }
#pragma unroll
    for (int i = 0; i < 4; i++) {
        size_t m = m0 + (tx << 2) + i;
        float4 o = {acc[i][0], acc[i][1], acc[i][2], acc[i][3]};
        *(float4*)(sim + ((size_t)b * NN + m) * NN + n0 + (ty << 2)) = o;
    }
}

// ---------------- lazy-greedy selection: one block per batch ----------------
// Submodularity: gains only shrink as S grows. Floating-point monotone too
// (fl(a-b), fmaxf, fp64 adds all monotone; cls>=0), so stale bounds are valid
// upper bounds and the lazy pop-recompute loop selects the IDENTICAL sequence
// as the reference's full recompute, smallest-index on ties (= jnp.argmax).
__global__ __launch_bounds__(576) void select_kernel(const float* __restrict__ sim,
                                                     const float* __restrict__ cls,
                                                     float* __restrict__ out_idx,
                                                     int* __restrict__ gsorted) {
    int b = blockIdx.x;
    const float* S = sim + (size_t)b * NN * NN;
    const float* C = cls + b * NN;
    __shared__ float cmax[NN];
    __shared__ double bounds[NN];
    __shared__ short epoch[NN];
    __shared__ unsigned char flags[NN];
    __shared__ double rv[9];
    __shared__ int ri[9];
    __shared__ int win;
    __shared__ int wtot[9], woff[9];
    int t = threadIdx.x, lane = t & 63, w = t >> 6;

    cmax[t] = 0.f; epoch[t] = 0; flags[t] = 0;
    __syncthreads();

    // initial gains (S = empty): wave w computes candidates [w*64, w*64+64)
    // NOTE: identical per-candidate routine/order as the recompute below.
    for (int i = 0; i < 64; i++) {
        int m = w * 64 + i;
        const float* row = S + (size_t)m * NN;  // sim symmetric & bitwise-equal
        double s = 0.0;
#pragma unroll
        for (int j = 0; j < 9; j++) {
            int n = j * 64 + lane;
            float d = row[n] - cmax[n];
            s += (double)fmaxf(d, 0.f);
        }
        for (int off = 32; off; off >>= 1) s += __shfl_xor(s, off);
        if (lane == 0) bounds[m] = s * (double)C[m];
    }
    __syncthreads();

    for (int k = 0; k < KK; k++) {
        int mstar;
        while (true) {
            // block argmax with smallest-index tie-break
            double v = bounds[t];
            int idx = t;
            for (int off = 32; off; off >>= 1) {
                double ov = __shfl_xor(v, off);
                int oi = __shfl_xor(idx, off);
                if (ov > v || (ov == v && oi < idx)) { v = ov; idx = oi; }
            }
            if (lane == 0) { rv[w] = v; ri[w] = idx; }
            __syncthreads();
            if (t == 0) {
                double bv = rv[0]; int bi = ri[0];
                for (int q = 1; q < 9; q++)
                    if (rv[q] > bv || (rv[q] == bv && ri[q] < bi)) { bv = rv[q]; bi = ri[q]; }
                win = bi;
            }
            __syncthreads();
            mstar = win;
            bool fresh = (epoch[mstar] == (short)k);  // uniform across block
            if (fresh) break;
            if (w == 0) {  // recompute by wave 0, same routine as init
                const float* row = S + (size_t)mstar * NN;
                double s = 0.0;
#pragma unroll
                for (int j = 0; j < 9; j++) {
                    int n = j * 64 + lane;
                    float d = row[n] - cmax[n];
                    s += (double)fmaxf(d, 0.f);
                }
                for (int off = 32; off; off >>= 1) s += __shfl_xor(s, off);
                if (lane == 0) { bounds[mstar] = s * (double)C[mstar]; epoch[mstar] = (short)k; }
            }
            __syncthreads();
        }
        if (t == 0) {
            flags[mstar] = 1;
            bounds[mstar] = -1.0;  // gains >= 0, sentinel excludes
            out_idx[b * KK + k] = (float)(mstar + 1);
        }
        __syncthreads();
        float sv = S[(size_t)mstar * NN + t];
        cmax[t] = fmaxf(cmax[t], sv);
        __syncthreads();
    }

    // sorted gather list = ascending scan of selected flags
    unsigned long long mask = __ballot(flags[t] != 0);
    int rank = __popcll(mask & ((1ull << lane) - 1));
    if (lane == 0) wtot[w] = __popcll(mask);
    __syncthreads();
    if (t == 0) { int a = 0; for (int q = 0; q < 9; q++) { woff[q] = a; a += wtot[q]; } }
    __syncthreads();
    if (flags[t]) gsorted[b * KK + woff[w] + rank] = t + 1;
}

// ---------------- gather: dominant_tokens[b,j,:] = hs[b, gsorted, :] --------
__global__ __launch_bounds__(256) void gather_kernel(const float* __restrict__ hs,
                                                     const int* __restrict__ gsorted,
                                                     float* __restrict__ out) {
    int blk = blockIdx.x;
    int b = blk >> 7, j = blk & 127;
    int row = gsorted[b * KK + j];
    const float4* src = (const float4*)(hs + ((size_t)b * HS_N + row) * DD);
    float4* dst = (float4*)(out + ((size_t)b * KK + j) * DD);
    dst[threadIdx.x] = src[threadIdx.x];
}

extern "C" void kernel_launch(void* const* d_in, const int* in_sizes, int n_in,
                              void* d_out, int out_size, void* d_ws, size_t ws_size,
                              hipStream_t stream) {
    const float* hs = (const float*)d_in[0];
    const float* cls = (const float*)d_in[1];
    // workspace layout: sim (42.5MB) | inv (73KB) | gsorted (16KB)
    float* sim = (float*)d_ws;
    float* inv = sim + (size_t)BB * NN * NN;
    int* gsorted = (int*)(inv + BB * NN);
    float* out_tokens = (float*)d_out;                       // [B,K,D] fp32
    float* out_idx = out_tokens + (size_t)BB * KK * DD;      // [B,K] indices as fp32

    norm_kernel<<<BB * NN, 256, 0, stream>>>(hs, inv);
    sim_kernel<<<dim3(9, 9, BB), 256, 0, stream>>>(hs, inv, sim);
    select_kernel<<<BB, 576, 0, stream>>>(sim, cls, out_idx, gsorted);
    gather_kernel<<<BB * KK, 256, 0, stream>>>(hs, gsorted, out_tokens);
}

// Round 2
// 1091.054 us; speedup vs baseline: 5.1015x; 5.1015x over previous
//
#include <hip/hip_runtime.h>

#define BB 32
#define NN 576
#define DD 1024
#define KK 128
#define HS_N 577

// ---------------- norm kernel: inv[b,n] = 1/||feats[b,n,:]|| ----------------
__global__ __launch_bounds__(256) void norm_kernel(const float* __restrict__ hs,
                                                   float* __restrict__ inv) {
    int row = blockIdx.x;              // b*NN + n
    int b = row / NN, n = row % NN;
    const float4* p = (const float4*)(hs + ((size_t)b * HS_N + n + 1) * DD);
    int t = threadIdx.x;
    float4 v = p[t];
    double s = (double)v.x * v.x + (double)v.y * v.y + (double)v.z * v.z + (double)v.w * v.w;
    for (int off = 32; off; off >>= 1) s += __shfl_xor(s, off);
    __shared__ double wsum[4];
    int lane = t & 63, w = t >> 6;
    if (lane == 0) wsum[w] = s;
    __syncthreads();
    if (t == 0) {
        double tot = wsum[0] + wsum[1] + wsum[2] + wsum[3];
        inv[row] = 1.0f / (float)sqrt(tot);
    }
}

// ---------------- sim GEMM (symmetric): only 45 upper-tri 64x64 tile pairs --
#define KC 16
#define LDT 68   // padded LDS stride
#define TLD 68   // transpose-bounce stride
__global__ __launch_bounds__(256) void sim_kernel(const float* __restrict__ hs,
                                                  const float* __restrict__ inv,
                                                  float* __restrict__ sim) {
    int b = blockIdx.z;
    int l = blockIdx.x;                // 0..44 -> (ti,tj), ti<=tj
    int ti = 0;
    while (l >= 9 - ti) { l -= 9 - ti; ti++; }
    int tj = ti + l;
    int m0 = ti * 64, n0 = tj * 64;
    const float* feats = hs + ((size_t)b * HS_N + 1) * DD;
    __shared__ float As[KC * LDT];
    __shared__ float Bs[KC * LDT];
    __shared__ float tile[64 * TLD];
    int t = threadIdx.x;
    int lrow = t >> 2, lc4 = (t & 3) << 2;     // 64 rows x 4 float4-cols
    float invA = inv[b * NN + m0 + lrow];
    float invB = inv[b * NN + n0 + lrow];
    const float* gA = feats + (size_t)(m0 + lrow) * DD + lc4;
    const float* gB = feats + (size_t)(n0 + lrow) * DD + lc4;
    int tx = t & 15, ty = t >> 4;
    float acc[4][4] = {};
    for (int k0 = 0; k0 < DD; k0 += KC) {
        float4 a = *(const float4*)(gA + k0);
        float4 bv = *(const float4*)(gB + k0);
        __syncthreads();
        // store transposed [k][m], scaled at load (matches reference normalize-then-dot)
        As[(lc4 + 0) * LDT + lrow] = a.x * invA;
        As[(lc4 + 1) * LDT + lrow] = a.y * invA;
        As[(lc4 + 2) * LDT + lrow] = a.z * invA;
        As[(lc4 + 3) * LDT + lrow] = a.w * invA;
        Bs[(lc4 + 0) * LDT + lrow] = bv.x * invB;
        Bs[(lc4 + 1) * LDT + lrow] = bv.y * invB;
        Bs[(lc4 + 2) * LDT + lrow] = bv.z * invB;
        Bs[(lc4 + 3) * LDT + lrow] = bv.w * invB;
        __syncthreads();
#pragma unroll
        for (int kk = 0; kk < KC; kk++) {
            float4 av = *(const float4*)&As[kk * LDT + (tx << 2)];
            float4 bw = *(const float4*)&Bs[kk * LDT + (ty << 2)];
            float aa[4] = {av.x, av.y, av.z, av.w};
            float bb[4] = {bw.x, bw.y, bw.z, bw.w};
#pragma unroll
            for (int i = 0; i < 4; i++)
#pragma unroll
                for (int j = 0; j < 4; j++) acc[i][j] += aa[i] * bb[j];
        }
    }
    // normal-orientation tile write (coalesced float4)
#pragma unroll
    for (int i = 0; i < 4; i++) {
        size_t m = m0 + (tx << 2) + i;
        float4 o = {acc[i][0], acc[i][1], acc[i][2], acc[i][3]};
        *(float4*)(sim + ((size_t)b * NN + m) * NN + n0 + (ty << 2)) = o;
    }
    if (ti != tj) {
        // mirror tile via LDS bounce; same float values -> bitwise symmetric
        __syncthreads();
#pragma unroll
        for (int i = 0; i < 4; i++) {
            float4 o = {acc[i][0], acc[i][1], acc[i][2], acc[i][3]};
            *(float4*)&tile[((tx << 2) + i) * TLD + (ty << 2)] = o;
        }
        __syncthreads();
#pragma unroll
        for (int r = 0; r < 4; r++) {
            int a = (tx << 2) + r;                 // local n index (output row)
            float4 o;
            o.x = tile[((ty << 2) + 0) * TLD + a];
            o.y = tile[((ty << 2) + 1) * TLD + a];
            o.z = tile[((ty << 2) + 2) * TLD + a];
            o.w = tile[((ty << 2) + 3) * TLD + a];
            *(float4*)(sim + ((size_t)b * NN + n0 + a) * NN + m0 + (ty << 2)) = o;
        }
    }
}

// ------- selection: exact incremental gain maintenance, one block/batch -----
// gain[m] = sum_n max(sim[m,n]-cmax[n],0) held in fp64 register of thread m.
// Per step: one argmax, then delta-update only over columns whose cmax grew.
// sim bitwise symmetric -> column reads are coalesced row reads.
__global__ __launch_bounds__(576) void select_kernel(const float* __restrict__ sim,
                                                     const float* __restrict__ cls,
                                                     float* __restrict__ out_idx,
                                                     int* __restrict__ gsorted) {
    int b = blockIdx.x;
    const float* S = sim + (size_t)b * NN * NN;
    int t = threadIdx.x, lane = t & 63, w = t >> 6;
    __shared__ float cmax[NN];
    __shared__ float oldv[NN];
    __shared__ int chlist[NN];
    __shared__ double rv[9];
    __shared__ int ri[9];
    __shared__ int win;
    __shared__ int wcnt[9], woff[9];
    __shared__ int chcount;

    float clsv = cls[b * NN + t];
    bool sel = false;
    cmax[t] = 0.f;

    // initial gains: column t of sim, coalesced, fixed order (deterministic)
    double g = 0.0;
    for (int n = 0; n < NN; n += 8) {
#pragma unroll
        for (int u = 0; u < 8; u++) {
            float s = S[(size_t)(n + u) * NN + t];
            g += (double)fmaxf(s, 0.f);
        }
    }
    __syncthreads();

    for (int k = 0; k < KK; k++) {
        // --- block argmax, smallest-index tie-break (= jnp.argmax) ---
        double v = sel ? -1.0 : g * (double)clsv;   // gains >= 0 for unselected
        int idx = t;
        for (int off = 32; off; off >>= 1) {
            double ov = __shfl_xor(v, off);
            int oi = __shfl_xor(idx, off);
            if (ov > v || (ov == v && oi < idx)) { v = ov; idx = oi; }
        }
        if (lane == 0) { rv[w] = v; ri[w] = idx; }
        __syncthreads();                           // b1
        if (t == 0) {
            double bv = rv[0]; int bi = ri[0];
            for (int q = 1; q < 9; q++)
                if (rv[q] > bv || (rv[q] == bv && ri[q] < bi)) { bv = rv[q]; bi = ri[q]; }
            win = bi;
        }
        __syncthreads();                           // b2
        int mstar = win;
        // --- cmax update + changed-set compaction ---
        float srow = S[(size_t)mstar * NN + t];
        float old = cmax[t];
        float nw = fmaxf(old, srow);
        bool ch = nw > old;
        unsigned long long mask = __ballot(ch);
        int rank = __popcll(mask & ((1ull << lane) - 1));
        if (lane == 0) wcnt[w] = __popcll(mask);
        oldv[t] = old;
        cmax[t] = nw;
        if (t == mstar) { sel = true; out_idx[b * KK + k] = (float)(mstar + 1); }
        __syncthreads();                           // b3
        if (t == 0) { int a = 0; for (int q = 0; q < 9; q++) { woff[q] = a; a += wcnt[q]; } chcount = a; }
        __syncthreads();                           // b4
        if (ch) chlist[woff[w] + rank] = t;
        __syncthreads();                           // b5
        // --- incremental gain update over changed columns (coalesced) ---
        int cc = chcount;
        if (cc > 0) {
            int n = chlist[0];
            float s = S[(size_t)n * NN + t];
            for (int j = 0; j < cc; j++) {
                float cur = s;
                int ncur = n;
                if (j + 1 < cc) { n = chlist[j + 1]; s = S[(size_t)n * NN + t]; }
                float o = oldv[ncur], nv2 = cmax[ncur];
                g += (double)fmaxf(cur - nv2, 0.f) - (double)fmaxf(cur - o, 0.f);
            }
        }
    }

    // sorted gather list = ascending scan of selected flags
    unsigned long long mask = __ballot(sel);
    int rank = __popcll(mask & ((1ull << lane) - 1));
    if (lane == 0) wcnt[w] = __popcll(mask);
    __syncthreads();
    if (t == 0) { int a = 0; for (int q = 0; q < 9; q++) { woff[q] = a; a += wcnt[q]; } }
    __syncthreads();
    if (sel) gsorted[b * KK + woff[w] + rank] = t + 1;
}

// ---------------- gather: dominant_tokens[b,j,:] = hs[b, gsorted, :] --------
__global__ __launch_bounds__(256) void gather_kernel(const float* __restrict__ hs,
                                                     const int* __restrict__ gsorted,
                                                     float* __restrict__ out) {
    int blk = blockIdx.x;
    int b = blk >> 7, j = blk & 127;
    int row = gsorted[b * KK + j];
    const float4* src = (const float4*)(hs + ((size_t)b * HS_N + row) * DD);
    float4* dst = (float4*)(out + ((size_t)b * KK + j) * DD);
    dst[threadIdx.x] = src[threadIdx.x];
}

extern "C" void kernel_launch(void* const* d_in, const int* in_sizes, int n_in,
                              void* d_out, int out_size, void* d_ws, size_t ws_size,
                              hipStream_t stream) {
    const float* hs = (const float*)d_in[0];
    const float* cls = (const float*)d_in[1];
    // workspace layout: sim (42.5MB) | inv (73KB) | gsorted (16KB)
    float* sim = (float*)d_ws;
    float* inv = sim + (size_t)BB * NN * NN;
    int* gsorted = (int*)(inv + BB * NN);
    float* out_tokens = (float*)d_out;                       // [B,K,D] fp32
    float* out_idx = out_tokens + (size_t)BB * KK * DD;      // [B,K] indices as fp32

    norm_kernel<<<BB * NN, 256, 0, stream>>>(hs, inv);
    sim_kernel<<<dim3(45, 1, BB), 256, 0, stream>>>(hs, inv, sim);
    select_kernel<<<BB, 576, 0, stream>>>(sim, cls, out_idx, gsorted);
    gather_kernel<<<BB * KK, 256, 0, stream>>>(hs, gsorted, out_tokens);
}

// Round 3
// 891.763 us; speedup vs baseline: 6.2416x; 1.2235x over previous
//
#include <hip/hip_runtime.h>

#define BB 32
#define NN 576
#define DD 1024
#define KK 128
#define HS_N 577

// ---------------- norm kernel: inv[b,n] = 1/||feats[b,n,:]|| ----------------
__global__ __launch_bounds__(256) void norm_kernel(const float* __restrict__ hs,
                                                   float* __restrict__ inv) {
    int row = blockIdx.x;              // b*NN + n
    int b = row / NN, n = row % NN;
    const float4* p = (const float4*)(hs + ((size_t)b * HS_N + n + 1) * DD);
    int t = threadIdx.x;
    float4 v = p[t];
    double s = (double)v.x * v.x + (double)v.y * v.y + (double)v.z * v.z + (double)v.w * v.w;
    for (int off = 32; off; off >>= 1) s += __shfl_xor(s, off);
    __shared__ double wsum[4];
    int lane = t & 63, w = t >> 6;
    if (lane == 0) wsum[w] = s;
    __syncthreads();
    if (t == 0) {
        double tot = wsum[0] + wsum[1] + wsum[2] + wsum[3];
        inv[row] = 1.0f / (float)sqrt(tot);
    }
}

// ---------------- sim GEMM (symmetric): only 45 upper-tri 64x64 tile pairs --
#define KC 16
#define LDT 68   // padded LDS stride
#define TLD 68   // transpose-bounce stride
__global__ __launch_bounds__(256) void sim_kernel(const float* __restrict__ hs,
                                                  const float* __restrict__ inv,
                                                  float* __restrict__ sim) {
    int b = blockIdx.z;
    int l = blockIdx.x;                // 0..44 -> (ti,tj), ti<=tj
    int ti = 0;
    while (l >= 9 - ti) { l -= 9 - ti; ti++; }
    int tj = ti + l;
    int m0 = ti * 64, n0 = tj * 64;
    const float* feats = hs + ((size_t)b * HS_N + 1) * DD;
    __shared__ float As[KC * LDT];
    __shared__ float Bs[KC * LDT];
    __shared__ float tile[64 * TLD];
    int t = threadIdx.x;
    int lrow = t >> 2, lc4 = (t & 3) << 2;     // 64 rows x 4 float4-cols
    float invA = inv[b * NN + m0 + lrow];
    float invB = inv[b * NN + n0 + lrow];
    const float* gA = feats + (size_t)(m0 + lrow) * DD + lc4;
    const float* gB = feats + (size_t)(n0 + lrow) * DD + lc4;
    int tx = t & 15, ty = t >> 4;
    float acc[4][4] = {};
    for (int k0 = 0; k0 < DD; k0 += KC) {
        float4 a = *(const float4*)(gA + k0);
        float4 bv = *(const float4*)(gB + k0);
        __syncthreads();
        // store transposed [k][m], scaled at load (matches reference normalize-then-dot)
        As[(lc4 + 0) * LDT + lrow] = a.x * invA;
        As[(lc4 + 1) * LDT + lrow] = a.y * invA;
        As[(lc4 + 2) * LDT + lrow] = a.z * invA;
        As[(lc4 + 3) * LDT + lrow] = a.w * invA;
        Bs[(lc4 + 0) * LDT + lrow] = bv.x * invB;
        Bs[(lc4 + 1) * LDT + lrow] = bv.y * invB;
        Bs[(lc4 + 2) * LDT + lrow] = bv.z * invB;
        Bs[(lc4 + 3) * LDT + lrow] = bv.w * invB;
        __syncthreads();
#pragma unroll
        for (int kk = 0; kk < KC; kk++) {
            float4 av = *(const float4*)&As[kk * LDT + (tx << 2)];
            float4 bw = *(const float4*)&Bs[kk * LDT + (ty << 2)];
            float aa[4] = {av.x, av.y, av.z, av.w};
            float bb[4] = {bw.x, bw.y, bw.z, bw.w};
#pragma unroll
            for (int i = 0; i < 4; i++)
#pragma unroll
                for (int j = 0; j < 4; j++) acc[i][j] += aa[i] * bb[j];
        }
    }
    // normal-orientation tile write (coalesced float4)
#pragma unroll
    for (int i = 0; i < 4; i++) {
        size_t m = m0 + (tx << 2) + i;
        float4 o = {acc[i][0], acc[i][1], acc[i][2], acc[i][3]};
        *(float4*)(sim + ((size_t)b * NN + m) * NN + n0 + (ty << 2)) = o;
    }
    if (ti != tj) {
        // mirror tile via LDS bounce; same float values -> bitwise symmetric
        __syncthreads();
#pragma unroll
        for (int i = 0; i < 4; i++) {
            float4 o = {acc[i][0], acc[i][1], acc[i][2], acc[i][3]};
            *(float4*)&tile[((tx << 2) + i) * TLD + (ty << 2)] = o;
        }
        __syncthreads();
#pragma unroll
        for (int r = 0; r < 4; r++) {
            int a = (tx << 2) + r;                 // local n index (output row)
            float4 o;
            o.x = tile[((ty << 2) + 0) * TLD + a];
            o.y = tile[((ty << 2) + 1) * TLD + a];
            o.z = tile[((ty << 2) + 2) * TLD + a];
            o.w = tile[((ty << 2) + 3) * TLD + a];
            *(float4*)(sim + ((size_t)b * NN + n0 + a) * NN + m0 + (ty << 2)) = o;
        }
    }
}

// ------- selection: exact incremental gain maintenance, one block/batch -----
// gain[m] = sum_n max(sim[m,n]-cmax[n],0) held in fp64 register of thread m.
// Per step: ONE argmax (3 barriers total), then 8-deep-ILP delta-update over
// the columns whose cmax grew. sim bitwise symmetric -> column = row reads.
// fp64 accumulation, fixed ascending-n order each step -> deterministic.
__global__ __launch_bounds__(576) void select_kernel(const float* __restrict__ sim,
                                                     const float* __restrict__ cls,
                                                     float* __restrict__ out_idx,
                                                     int* __restrict__ gsorted) {
    int b = blockIdx.x;
    const float* S = sim + (size_t)b * NN * NN;
    int t = threadIdx.x, lane = t & 63, w = t >> 6;
    __shared__ float cmax[NN];
    __shared__ float oldv[NN];
    __shared__ int chlist[NN];     // flat compacted, ascending n
    __shared__ double rv[9];
    __shared__ int ri[9];
    __shared__ int wcnt[9];
    __shared__ int chcount;

    float clsv = cls[b * NN + t];
    bool sel = false;
    cmax[t] = 0.f;

    // initial gains: column t of sim, coalesced, fixed order (deterministic)
    double g = 0.0;
    for (int n = 0; n < NN; n += 8) {
#pragma unroll
        for (int u = 0; u < 8; u++) {
            float s = S[(size_t)(n + u) * NN + t];
            g += (double)fmaxf(s, 0.f);
        }
    }
    int cc = 0;  // changed-count from previous step (0 for step 0)

    for (int k = 0; k < KK; k++) {
        // --- phase 1: delta-update g over changed columns, 8-deep ILP ------
        for (int j = 0; j < cc; j += 8) {
            int n_[8]; float s_[8];
#pragma unroll
            for (int u = 0; u < 8; u++) {
                int i = j + u;
                n_[u] = (i < cc) ? chlist[i] : 0;
            }
#pragma unroll
            for (int u = 0; u < 8; u++)
                if (j + u < cc) s_[u] = S[(size_t)n_[u] * NN + t];
#pragma unroll
            for (int u = 0; u < 8; u++)
                if (j + u < cc) {
                    float o = oldv[n_[u]], nv = cmax[n_[u]];
                    g += (double)fmaxf(s_[u] - nv, 0.f) - (double)fmaxf(s_[u] - o, 0.f);
                }
        }
        // --- phase 2: wave-level argmax, smallest-index tie-break ----------
        double v = sel ? -1.0 : g * (double)clsv;   // gains >= 0 for unselected
        int idx = t;
        for (int off = 32; off; off >>= 1) {
            double ov = __shfl_xor(v, off);
            int oi = __shfl_xor(idx, off);
            if (ov > v || (ov == v && oi < idx)) { v = ov; idx = oi; }
        }
        if (lane == 0) { rv[w] = v; ri[w] = idx; }
        __syncthreads();                           // A
        // --- phase 3: every thread scans the 9 slots (broadcast reads) -----
        double bv = rv[0]; int mstar = ri[0];
#pragma unroll
        for (int q = 1; q < 9; q++) {
            double qv = rv[q]; int qi = ri[q];
            if (qv > bv || (qv == bv && qi < mstar)) { bv = qv; mstar = qi; }
        }
        float srow = S[(size_t)mstar * NN + t];
        float old = cmax[t];
        float nw = fmaxf(old, srow);
        bool ch = nw > old;
        unsigned long long mask = __ballot(ch);
        int rank = __popcll(mask & ((1ull << lane) - 1));
        if (lane == 0) wcnt[w] = __popcll(mask);
        oldv[t] = old;
        cmax[t] = nw;
        if (t == mstar) { sel = true; out_idx[b * KK + k] = (float)(mstar + 1); }
        __syncthreads();                           // B
        // --- phase 4: flat compaction (deterministic ascending-n order) ----
        int pre = 0, tot = 0;
#pragma unroll
        for (int q = 0; q < 9; q++) { int c = wcnt[q]; if (q < 9) { if (q < w) pre += c; tot += c; } }
        if (ch) chlist[pre + rank] = t;
        cc = tot;
        __syncthreads();                           // C
    }

    // sorted gather list = ascending scan of selected flags
    unsigned long long mask = __ballot(sel);
    int rank = __popcll(mask & ((1ull << lane) - 1));
    if (lane == 0) wcnt[w] = __popcll(mask);
    __syncthreads();
    int pre = 0;
#pragma unroll
    for (int q = 0; q < 9; q++) if (q < w) pre += wcnt[q];
    if (sel) gsorted[b * KK + pre + rank] = t + 1;
}

// ---------------- gather: dominant_tokens[b,j,:] = hs[b, gsorted, :] --------
__global__ __launch_bounds__(256) void gather_kernel(const float* __restrict__ hs,
                                                     const int* __restrict__ gsorted,
                                                     float* __restrict__ out) {
    int blk = blockIdx.x;
    int b = blk >> 7, j = blk & 127;
    int row = gsorted[b * KK + j];
    const float4* src = (const float4*)(hs + ((size_t)b * HS_N + row) * DD);
    float4* dst = (float4*)(out + ((size_t)b * KK + j) * DD);
    dst[threadIdx.x] = src[threadIdx.x];
}

extern "C" void kernel_launch(void* const* d_in, const int* in_sizes, int n_in,
                              void* d_out, int out_size, void* d_ws, size_t ws_size,
                              hipStream_t stream) {
    const float* hs = (const float*)d_in[0];
    const float* cls = (const float*)d_in[1];
    // workspace layout: sim (42.5MB) | inv (73KB) | gsorted (16KB)
    float* sim = (float*)d_ws;
    float* inv = sim + (size_t)BB * NN * NN;
    int* gsorted = (int*)(inv + BB * NN);
    float* out_tokens = (float*)d_out;                       // [B,K,D] fp32
    float* out_idx = out_tokens + (size_t)BB * KK * DD;      // [B,K] indices as fp32

    norm_kernel<<<BB * NN, 256, 0, stream>>>(hs, inv);
    sim_kernel<<<dim3(45, 1, BB), 256, 0, stream>>>(hs, inv, sim);
    select_kernel<<<BB, 576, 0, stream>>>(sim, cls, out_idx, gsorted);
    gather_kernel<<<BB * KK, 256, 0, stream>>>(hs, gsorted, out_tokens);
}